// Round 7
// baseline (262.717 us; speedup 1.0000x reference)
//
#include <hip/hip_runtime.h>

// WindowAttention: B=8, C=128, H=W=256, ws=8, heads=4, d=32, n=64 tokens/window
// One block = one window (8192 blocks, 256 thr = 4 waves). Wave h owns head h.
// Projections/proj-GEMM: v_mfma_f32_16x16x32_bf16. Attention: v_mfma_f32_16x16x16_bf16,
// whose A/B k-mapping (k = (lane>>4)*4 + j) EXACTLY matches the projection MFMA's
// C/D layout (row = (lane>>4)*4 + r), so Q/K/V/P stay in registers: zero scratch
// LDS, zero cross-lane shuffles for fragments, pure-reg attention phase.
//   swapped  proj mfma(W,X): lane=tok, regs=d   -> A/B frags of S^T=mfma16(K,Q)
//   S^T out:                 lane=q,   regs=key -> A frag of PV
//   non-swap proj mfma(X,W): lane=d,   regs=tok -> B frag of PV
// LDS: Xt[64][128]bf16 (swz (tok&15)<<4) -> Ot overlay. 16K used, padded to 40K
// to pin occupancy at 4 blocks/CU => 128-VGPR allocator budget (anti-spill; r1/r2/r6
// showed the allocator otherwise targets 64 VGPR and spills ~0.5GB).

#define HH    256
#define WWID  256
#define SCALE 0.17677669529663687f
#define LOG2E 1.44269504088896340736f

typedef float  f32x4  __attribute__((ext_vector_type(4)));
typedef __bf16 bf16x8 __attribute__((ext_vector_type(8)));
typedef __bf16 bf16x4 __attribute__((ext_vector_type(4)));
typedef __bf16 bf16x2 __attribute__((ext_vector_type(2)));
typedef short  s16x4  __attribute__((ext_vector_type(4)));

__device__ __forceinline__ s16x4 pack4(f32x4 v) {
  bf16x4 b = {(__bf16)v[0], (__bf16)v[1], (__bf16)v[2], (__bf16)v[3]};
  return __builtin_bit_cast(s16x4, b);
}

#if __has_builtin(__builtin_amdgcn_mfma_f32_16x16x16bf16_1k)
__device__ __forceinline__ f32x4 mfma16(s16x4 a, s16x4 b, f32x4 c) {
  return __builtin_amdgcn_mfma_f32_16x16x16bf16_1k(a, b, c, 0, 0, 0);
}
#else
__device__ __forceinline__ f32x4 mfma16(s16x4 a, s16x4 b, f32x4 c) {
  asm("v_mfma_f32_16x16x16_bf16 %0, %1, %2, %0" : "+v"(c) : "v"(a), "v"(b));
  return c;
}
#endif

__global__ void prep_weights(const float* __restrict__ wqkv,
                             const float* __restrict__ wproj,
                             __bf16* __restrict__ wbf) {
  int i = blockIdx.x * 256 + threadIdx.x;          // 65536 total
  float v = (i < 49152) ? wqkv[i] : wproj[i - 49152];
  if (i < 16384) v *= SCALE * LOG2E;               // fold softmax scale + log2e into Wq
  wbf[i] = (__bf16)v;
}

__global__ __launch_bounds__(256, 2)
void winattn_main(const float* __restrict__ x,
                  const __bf16* __restrict__ wqkv,   // [384][128] bf16 (Q rows pre-scaled)
                  const __bf16* __restrict__ wproj,  // [128][128] bf16
                  const float* __restrict__ bproj,
                  float* __restrict__ out) {
  __shared__ __align__(16) char smem[40960];   // 16K used; padded to pin 4 blocks/CU

  const int tid  = threadIdx.x;
  const int lane = tid & 63;
  const int wv   = tid >> 6;       // wave id == head id
  const int l15  = lane & 15;
  const int l4   = lane >> 4;

  // XCD-aware swizzle: XCD k owns batch k; horizontally adjacent windows
  // (sharing 64B lines of x/out) are 8 apart in bid -> same XCD, adjacent in time.
  const int bid = blockIdx.x;
  const int win = ((bid & 7) << 10) | (bid >> 3);
  const int b   = win >> 10;
  const int wy  = (win >> 5) & 31;
  const int wx  = win & 31;
  const int gy0 = wy * 8, gx0 = wx * 8;

  // ---------------- Phase A: load window -> Xt[tok][c] bf16 (swz &15) ----------------
  #pragma unroll
  for (int it = 0; it < 4; ++it) {
    int idx   = tid + it * 256;        // 1024 tasks: (cpair 64) x (ty 8) x (tx4 2)
    int cpair = idx >> 4;
    int r     = idx & 15;
    int ty    = r >> 1, tx4 = r & 1;
    const float* px = x + (((size_t)(b * 128 + 2 * cpair) * HH + gy0 + ty) * WWID + gx0 + tx4 * 4);
    float4 v0 = *(const float4*)px;
    float4 v1 = *(const float4*)(px + (size_t)HH * WWID);
    float a0[4] = {v0.x, v0.y, v0.z, v0.w};
    float a1[4] = {v1.x, v1.y, v1.z, v1.w};
    #pragma unroll
    for (int i = 0; i < 4; ++i) {
      int tok = ty * 8 + tx4 * 4 + i;
      bf16x2 w2 = {(__bf16)a0[i], (__bf16)a1[i]};
      int byte = (tok * 256 + cpair * 4) ^ ((tok & 15) << 4);
      *(bf16x2*)(smem + byte) = w2;
    }
  }
  __syncthreads();

  // Xt (and later Ot) fragment; A- and B-operand lane mappings are identical.
  #define XT_AFRAG(mt, kt) \
    (*(const bf16x8*)(smem + ((((mt) * 16 + l15) * 256 + ((kt) * 32 + l4 * 8) * 2) ^ \
                              ((((mt) * 16 + l15) & 15) << 4))))

  // ---------------- Phase B1: Q & K fused, SWAPPED -> registers ----------------
  // accQ/accK[nt2][mt]: lane l15 = tok (mt*16+l15), reg r = d (nt2*16+l4*4+r)
  s16x4 qb[2][4], kb[2][4];
  {
    f32x4 accQ[2][4] = {}, accK[2][4] = {};
    #pragma unroll
    for (int kt = 0; kt < 4; ++kt) {
      bf16x8 xf[4];
      #pragma unroll
      for (int mt = 0; mt < 4; ++mt) xf[mt] = XT_AFRAG(mt, kt);
      #pragma unroll
      for (int nt2 = 0; nt2 < 2; ++nt2) {
        bf16x8 wq = *(const bf16x8*)(wqkv + (size_t)(wv * 32 + nt2 * 16 + l15) * 128 + kt * 32 + l4 * 8);
        bf16x8 wk = *(const bf16x8*)(wqkv + (size_t)(128 + wv * 32 + nt2 * 16 + l15) * 128 + kt * 32 + l4 * 8);
        #pragma unroll
        for (int mt = 0; mt < 4; ++mt) {
          accQ[nt2][mt] = __builtin_amdgcn_mfma_f32_16x16x32_bf16(wq, xf[mt], accQ[nt2][mt], 0, 0, 0);
          accK[nt2][mt] = __builtin_amdgcn_mfma_f32_16x16x32_bf16(wk, xf[mt], accK[nt2][mt], 0, 0, 0);
        }
      }
    }
    #pragma unroll
    for (int nt2 = 0; nt2 < 2; ++nt2)
      #pragma unroll
      for (int mt = 0; mt < 4; ++mt) {
        qb[nt2][mt] = pack4(accQ[nt2][mt]);
        kb[nt2][mt] = pack4(accK[nt2][mt]);
      }
  }

  // ---------------- Phase B2: V non-swapped -> registers ----------------
  // accV[nt2][mt]: lane l15 = d (nt2*16+l15), reg r = tok (mt*16+l4*4+r)
  s16x4 vb[2][4];
  {
    f32x4 accV[2][4] = {};
    #pragma unroll
    for (int kt = 0; kt < 4; ++kt) {
      bf16x8 xf[4];
      #pragma unroll
      for (int mt = 0; mt < 4; ++mt) xf[mt] = XT_AFRAG(mt, kt);
      #pragma unroll
      for (int nt2 = 0; nt2 < 2; ++nt2) {
        bf16x8 wf = *(const bf16x8*)(wqkv + (size_t)(256 + wv * 32 + nt2 * 16 + l15) * 128 + kt * 32 + l4 * 8);
        #pragma unroll
        for (int mt = 0; mt < 4; ++mt)
          accV[nt2][mt] = __builtin_amdgcn_mfma_f32_16x16x32_bf16(xf[mt], wf, accV[nt2][mt], 0, 0, 0);
      }
    }
    #pragma unroll
    for (int nt2 = 0; nt2 < 2; ++nt2)
      #pragma unroll
      for (int mt = 0; mt < 4; ++mt) vb[nt2][mt] = pack4(accV[nt2][mt]);
  }

  // ---------------- Phase C: attention, pure registers (no LDS) ----------------
  // S^T[key][q] = sum_nt2 mfma16(K-chunk, Q-chunk): lane l15 = q, reg = key.
  f32x4 oacc[4][2] = {};   // [q-tile t][d-tile n]: lane l15 = d, reg r = q (l4*4+r)
  #pragma unroll
  for (int t = 0; t < 4; ++t) {
    f32x4 st[4];
    #pragma unroll
    for (int m = 0; m < 4; ++m) {
      f32x4 z = {0.f, 0.f, 0.f, 0.f};
      st[m] = mfma16(kb[0][m], qb[0][t], z);
      st[m] = mfma16(kb[1][m], qb[1][t], st[m]);
    }
    float mx = st[0][0];
    #pragma unroll
    for (int m = 0; m < 4; ++m)
      #pragma unroll
      for (int r = 0; r < 4; ++r) mx = fmaxf(mx, st[m][r]);
    mx = fmaxf(mx, __shfl_xor(mx, 16));
    mx = fmaxf(mx, __shfl_xor(mx, 32));
    float p[4][4];
    float sm = 0.f;
    #pragma unroll
    for (int m = 0; m < 4; ++m)
      #pragma unroll
      for (int r = 0; r < 4; ++r) {
        p[m][r] = __builtin_amdgcn_exp2f(st[m][r] - mx);
        sm += p[m][r];
      }
    sm += __shfl_xor(sm, 16);
    sm += __shfl_xor(sm, 32);
    float inv = __builtin_amdgcn_rcpf(sm);
    s16x4 ap[4];
    #pragma unroll
    for (int m = 0; m < 4; ++m) {
      f32x4 pn = {p[m][0] * inv, p[m][1] * inv, p[m][2] * inv, p[m][3] * inv};
      ap[m] = pack4(pn);
    }
    #pragma unroll
    for (int m = 0; m < 4; ++m)
      #pragma unroll
      for (int n = 0; n < 2; ++n)
        oacc[t][n] = mfma16(ap[m], vb[n][m], oacc[t][n]);
  }
  __syncthreads();   // all waves done reading Xt (B1/B2) -> overlay Ot onto Xt region

  // write Ot[64 tok][128 c] bf16 (lane l15 = d -> c; reg r = tok)
  #pragma unroll
  for (int t = 0; t < 4; ++t)
    #pragma unroll
    for (int n = 0; n < 2; ++n)
      #pragma unroll
      for (int r = 0; r < 4; ++r) {
        int tok  = t * 16 + l4 * 4 + r;
        int c    = wv * 32 + n * 16 + l15;
        int byte = (tok * 256 + c * 2) ^ ((tok & 15) << 4);
        *(__bf16*)(smem + byte) = (__bf16)oacc[t][n][r];
      }
  __syncthreads();

  // ---------------- Phase D: proj GEMM (x32; Ot frags shared across o-tiles) ----------------
  f32x4 pacc[2][4] = {};  // [o-tile][tok-tile]
  #pragma unroll
  for (int kt = 0; kt < 4; ++kt) {
    bf16x8 of[4];
    #pragma unroll
    for (int mt = 0; mt < 4; ++mt) of[mt] = XT_AFRAG(mt, kt);
    #pragma unroll
    for (int i = 0; i < 2; ++i) {
      bf16x8 wp = *(const bf16x8*)(wproj + (size_t)((wv * 2 + i) * 16 + l15) * 128 + kt * 32 + l4 * 8);
      #pragma unroll
      for (int mt = 0; mt < 4; ++mt)
        pacc[i][mt] = __builtin_amdgcn_mfma_f32_16x16x32_bf16(of[mt], wp, pacc[i][mt], 0, 0, 0);
    }
  }

  // ---------------- Phase E: direct float4 writeout + bias ----------------
  #pragma unroll
  for (int i = 0; i < 2; ++i) {
    int o = (wv * 2 + i) * 16 + l15;
    float bias = bproj[o];
    float* obase = out + (size_t)(b * 128 + o) * ((size_t)HH * WWID) + gy0 * WWID + gx0;
    #pragma unroll
    for (int mt = 0; mt < 4; ++mt) {
      int tok0 = mt * 16 + l4 * 4;            // 4 consecutive toks within one y-row
      int ty = tok0 >> 3, tx0 = tok0 & 7;
      float4 f = {pacc[i][mt][0] + bias, pacc[i][mt][1] + bias,
                  pacc[i][mt][2] + bias, pacc[i][mt][3] + bias};
      *(float4*)(obase + ty * WWID + tx0) = f;
    }
  }
}

extern "C" void kernel_launch(void* const* d_in, const int* in_sizes, int n_in,
                              void* d_out, int out_size, void* d_ws, size_t ws_size,
                              hipStream_t stream) {
  const float* x     = (const float*)d_in[0];
  const float* wqkv  = (const float*)d_in[1];
  const float* wproj = (const float*)d_in[2];
  const float* bproj = (const float*)d_in[3];
  float* out = (float*)d_out;

  __bf16* wbf = (__bf16*)d_ws;   // 65536 bf16 = 128 KiB scratch
  prep_weights<<<256, 256, 0, stream>>>(wqkv, wproj, wbf);
  winattn_main<<<8192, 256, 0, stream>>>(x, wbf, wbf + 49152, bproj, out);
}

// Round 8
// 261.046 us; speedup vs baseline: 1.0064x; 1.0064x over previous
//
#include <hip/hip_runtime.h>

// WindowAttention: B=8, C=128, H=W=256, ws=8, heads=4, d=32, n=64 tokens/window
// One block = one window (8192 blocks, 256 thr = 4 waves). Wave h owns head h.
// Projections/proj-GEMM: v_mfma_f32_16x16x32_bf16. Attention: v_mfma_f32_16x16x16_bf16,
// whose A/B k-mapping (k = (lane>>4)*4 + j) EXACTLY matches the projection MFMA's
// C/D layout (row = (lane>>4)*4 + r), so Q/K/V/P stay in registers: zero scratch
// LDS, zero cross-lane shuffles for fragments, pure-reg attention phase.
//   swapped  proj mfma(W,X): lane=tok, regs=d   -> A/B frags of S^T=mfma16(K,Q)
//   S^T out:                 lane=q,   regs=key -> A frag of PV
//   non-swap proj mfma(X,W): lane=d,   regs=tok -> B frag of PV
// LDS = 32 KiB total: [0,16K) Xt[64][128]bf16 (swz (tok&15)<<4, dead after B2);
// [16K,32K) Ot[64][128]bf16 (separate region -> no WAR barrier; 2 barriers total).
// 32K chosen for residency: 40K pad (r7) collapsed occupancy to ~1.7 blocks/CU
// (LDS granule rounds up); 32K regimes measured 32-42% occupancy (r4-r6).
// __launch_bounds__(256,2): spill-free allocation regime (r0/r3/r5/r7).

#define HH    256
#define WWID  256
#define SCALE 0.17677669529663687f
#define LOG2E 1.44269504088896340736f

typedef float  f32x4  __attribute__((ext_vector_type(4)));
typedef __bf16 bf16x8 __attribute__((ext_vector_type(8)));
typedef __bf16 bf16x4 __attribute__((ext_vector_type(4)));
typedef __bf16 bf16x2 __attribute__((ext_vector_type(2)));
typedef short  s16x4  __attribute__((ext_vector_type(4)));

#define OT_BASE 16384

__device__ __forceinline__ s16x4 pack4(f32x4 v) {
  bf16x4 b = {(__bf16)v[0], (__bf16)v[1], (__bf16)v[2], (__bf16)v[3]};
  return __builtin_bit_cast(s16x4, b);
}

#if __has_builtin(__builtin_amdgcn_mfma_f32_16x16x16bf16_1k)
__device__ __forceinline__ f32x4 mfma16(s16x4 a, s16x4 b, f32x4 c) {
  return __builtin_amdgcn_mfma_f32_16x16x16bf16_1k(a, b, c, 0, 0, 0);
}
#else
__device__ __forceinline__ f32x4 mfma16(s16x4 a, s16x4 b, f32x4 c) {
  asm("v_mfma_f32_16x16x16_bf16 %0, %1, %2, %0" : "+v"(c) : "v"(a), "v"(b));
  return c;
}
#endif

__global__ void prep_weights(const float* __restrict__ wqkv,
                             const float* __restrict__ wproj,
                             __bf16* __restrict__ wbf) {
  int i = blockIdx.x * 256 + threadIdx.x;          // 65536 total
  float v = (i < 49152) ? wqkv[i] : wproj[i - 49152];
  if (i < 16384) v *= SCALE * LOG2E;               // fold softmax scale + log2e into Wq
  wbf[i] = (__bf16)v;
}

__global__ __launch_bounds__(256, 2)
void winattn_main(const float* __restrict__ x,
                  const __bf16* __restrict__ wqkv,   // [384][128] bf16 (Q rows pre-scaled)
                  const __bf16* __restrict__ wproj,  // [128][128] bf16
                  const float* __restrict__ bproj,
                  float* __restrict__ out) {
  __shared__ __align__(16) char smem[32768];

  const int tid  = threadIdx.x;
  const int lane = tid & 63;
  const int wv   = tid >> 6;       // wave id == head id
  const int l15  = lane & 15;
  const int l4   = lane >> 4;

  // XCD-aware swizzle: XCD k owns batch k; horizontally adjacent windows
  // (sharing 64B lines of x/out) are 8 apart in bid -> same XCD, adjacent in time.
  const int bid = blockIdx.x;
  const int win = ((bid & 7) << 10) | (bid >> 3);
  const int b   = win >> 10;
  const int wy  = (win >> 5) & 31;
  const int wx  = win & 31;
  const int gy0 = wy * 8, gx0 = wx * 8;

  // ---------------- Phase A: load window -> Xt[tok][c] bf16 (swz &15) ----------------
  #pragma unroll
  for (int it = 0; it < 4; ++it) {
    int idx   = tid + it * 256;        // 1024 tasks: (cpair 64) x (ty 8) x (tx4 2)
    int cpair = idx >> 4;
    int r     = idx & 15;
    int ty    = r >> 1, tx4 = r & 1;
    const float* px = x + (((size_t)(b * 128 + 2 * cpair) * HH + gy0 + ty) * WWID + gx0 + tx4 * 4);
    float4 v0 = *(const float4*)px;
    float4 v1 = *(const float4*)(px + (size_t)HH * WWID);
    float a0[4] = {v0.x, v0.y, v0.z, v0.w};
    float a1[4] = {v1.x, v1.y, v1.z, v1.w};
    #pragma unroll
    for (int i = 0; i < 4; ++i) {
      int tok = ty * 8 + tx4 * 4 + i;
      bf16x2 w2 = {(__bf16)a0[i], (__bf16)a1[i]};
      int byte = (tok * 256 + cpair * 4) ^ ((tok & 15) << 4);
      *(bf16x2*)(smem + byte) = w2;
    }
  }
  __syncthreads();

  // Xt fragment; A- and B-operand lane mappings are identical.
  #define XT_AFRAG(mt, kt) \
    (*(const bf16x8*)(smem + ((((mt) * 16 + l15) * 256 + ((kt) * 32 + l4 * 8) * 2) ^ \
                              ((((mt) * 16 + l15) & 15) << 4))))
  // Ot fragment (same layout, separate 16K region)
  #define OT_AFRAG(mt, kt) \
    (*(const bf16x8*)(smem + OT_BASE + ((((mt) * 16 + l15) * 256 + ((kt) * 32 + l4 * 8) * 2) ^ \
                              ((((mt) * 16 + l15) & 15) << 4))))

  // ---------------- Phase B1: Q & K fused, SWAPPED -> registers ----------------
  // accQ/accK[nt2][mt]: lane l15 = tok (mt*16+l15), reg r = d (nt2*16+l4*4+r)
  s16x4 qb[2][4], kb[2][4];
  {
    f32x4 accQ[2][4] = {}, accK[2][4] = {};
    #pragma unroll
    for (int kt = 0; kt < 4; ++kt) {
      bf16x8 xf[4];
      #pragma unroll
      for (int mt = 0; mt < 4; ++mt) xf[mt] = XT_AFRAG(mt, kt);
      #pragma unroll
      for (int nt2 = 0; nt2 < 2; ++nt2) {
        bf16x8 wq = *(const bf16x8*)(wqkv + (size_t)(wv * 32 + nt2 * 16 + l15) * 128 + kt * 32 + l4 * 8);
        bf16x8 wk = *(const bf16x8*)(wqkv + (size_t)(128 + wv * 32 + nt2 * 16 + l15) * 128 + kt * 32 + l4 * 8);
        #pragma unroll
        for (int mt = 0; mt < 4; ++mt) {
          accQ[nt2][mt] = __builtin_amdgcn_mfma_f32_16x16x32_bf16(wq, xf[mt], accQ[nt2][mt], 0, 0, 0);
          accK[nt2][mt] = __builtin_amdgcn_mfma_f32_16x16x32_bf16(wk, xf[mt], accK[nt2][mt], 0, 0, 0);
        }
      }
    }
    #pragma unroll
    for (int nt2 = 0; nt2 < 2; ++nt2)
      #pragma unroll
      for (int mt = 0; mt < 4; ++mt) {
        qb[nt2][mt] = pack4(accQ[nt2][mt]);
        kb[nt2][mt] = pack4(accK[nt2][mt]);
      }
  }

  // ---------------- Phase B2: V non-swapped -> registers ----------------
  // accV[nt2][mt]: lane l15 = d (nt2*16+l15), reg r = tok (mt*16+l4*4+r)
  s16x4 vb[2][4];
  {
    f32x4 accV[2][4] = {};
    #pragma unroll
    for (int kt = 0; kt < 4; ++kt) {
      bf16x8 xf[4];
      #pragma unroll
      for (int mt = 0; mt < 4; ++mt) xf[mt] = XT_AFRAG(mt, kt);
      #pragma unroll
      for (int nt2 = 0; nt2 < 2; ++nt2) {
        bf16x8 wf = *(const bf16x8*)(wqkv + (size_t)(256 + wv * 32 + nt2 * 16 + l15) * 128 + kt * 32 + l4 * 8);
        #pragma unroll
        for (int mt = 0; mt < 4; ++mt)
          accV[nt2][mt] = __builtin_amdgcn_mfma_f32_16x16x32_bf16(xf[mt], wf, accV[nt2][mt], 0, 0, 0);
      }
    }
    #pragma unroll
    for (int nt2 = 0; nt2 < 2; ++nt2)
      #pragma unroll
      for (int mt = 0; mt < 4; ++mt) vb[nt2][mt] = pack4(accV[nt2][mt]);
  }

  // ---------------- Phase C: attention, pure registers (no LDS) ----------------
  // S^T[key][q] = sum_nt2 mfma16(K-chunk, Q-chunk): lane l15 = q, reg = key.
  f32x4 oacc[4][2] = {};   // [q-tile t][d-tile n]: lane l15 = d, reg r = q (l4*4+r)
  #pragma unroll
  for (int t = 0; t < 4; ++t) {
    f32x4 st[4];
    #pragma unroll
    for (int m = 0; m < 4; ++m) {
      f32x4 z = {0.f, 0.f, 0.f, 0.f};
      st[m] = mfma16(kb[0][m], qb[0][t], z);
      st[m] = mfma16(kb[1][m], qb[1][t], st[m]);
    }
    float mx = st[0][0];
    #pragma unroll
    for (int m = 0; m < 4; ++m)
      #pragma unroll
      for (int r = 0; r < 4; ++r) mx = fmaxf(mx, st[m][r]);
    mx = fmaxf(mx, __shfl_xor(mx, 16));
    mx = fmaxf(mx, __shfl_xor(mx, 32));
    float p[4][4];
    float sm = 0.f;
    #pragma unroll
    for (int m = 0; m < 4; ++m)
      #pragma unroll
      for (int r = 0; r < 4; ++r) {
        p[m][r] = __builtin_amdgcn_exp2f(st[m][r] - mx);
        sm += p[m][r];
      }
    sm += __shfl_xor(sm, 16);
    sm += __shfl_xor(sm, 32);
    float inv = __builtin_amdgcn_rcpf(sm);
    s16x4 ap[4];
    #pragma unroll
    for (int m = 0; m < 4; ++m) {
      f32x4 pn = {p[m][0] * inv, p[m][1] * inv, p[m][2] * inv, p[m][3] * inv};
      ap[m] = pack4(pn);
    }
    #pragma unroll
    for (int m = 0; m < 4; ++m)
      #pragma unroll
      for (int n = 0; n < 2; ++n)
        oacc[t][n] = mfma16(ap[m], vb[n][m], oacc[t][n]);
  }

  // write Ot[64 tok][128 c] bf16 into the SEPARATE region (no WAR barrier needed)
  #pragma unroll
  for (int t = 0; t < 4; ++t)
    #pragma unroll
    for (int n = 0; n < 2; ++n)
      #pragma unroll
      for (int r = 0; r < 4; ++r) {
        int tok  = t * 16 + l4 * 4 + r;
        int c    = wv * 32 + n * 16 + l15;
        int byte = OT_BASE + ((tok * 256 + c * 2) ^ ((tok & 15) << 4));
        *(__bf16*)(smem + byte) = (__bf16)oacc[t][n][r];
      }
  __syncthreads();   // Ot complete -> D may read all heads' columns

  // ---------------- Phase D: proj GEMM (x32; Ot frags shared across o-tiles) ----------------
  f32x4 pacc[2][4] = {};  // [o-tile][tok-tile]
  #pragma unroll
  for (int kt = 0; kt < 4; ++kt) {
    bf16x8 of[4];
    #pragma unroll
    for (int mt = 0; mt < 4; ++mt) of[mt] = OT_AFRAG(mt, kt);
    #pragma unroll
    for (int i = 0; i < 2; ++i) {
      bf16x8 wp = *(const bf16x8*)(wproj + (size_t)((wv * 2 + i) * 16 + l15) * 128 + kt * 32 + l4 * 8);
      #pragma unroll
      for (int mt = 0; mt < 4; ++mt)
        pacc[i][mt] = __builtin_amdgcn_mfma_f32_16x16x32_bf16(of[mt], wp, pacc[i][mt], 0, 0, 0);
    }
  }

  // ---------------- Phase E: direct float4 writeout + bias ----------------
  #pragma unroll
  for (int i = 0; i < 2; ++i) {
    int o = (wv * 2 + i) * 16 + l15;
    float bias = bproj[o];
    float* obase = out + (size_t)(b * 128 + o) * ((size_t)HH * WWID) + gy0 * WWID + gx0;
    #pragma unroll
    for (int mt = 0; mt < 4; ++mt) {
      int tok0 = mt * 16 + l4 * 4;            // 4 consecutive toks within one y-row
      int ty = tok0 >> 3, tx0 = tok0 & 7;
      float4 f = {pacc[i][mt][0] + bias, pacc[i][mt][1] + bias,
                  pacc[i][mt][2] + bias, pacc[i][mt][3] + bias};
      *(float4*)(obase + ty * WWID + tx0) = f;
    }
  }
}

extern "C" void kernel_launch(void* const* d_in, const int* in_sizes, int n_in,
                              void* d_out, int out_size, void* d_ws, size_t ws_size,
                              hipStream_t stream) {
  const float* x     = (const float*)d_in[0];
  const float* wqkv  = (const float*)d_in[1];
  const float* wproj = (const float*)d_in[2];
  const float* bproj = (const float*)d_in[3];
  float* out = (float*)d_out;

  __bf16* wbf = (__bf16*)d_ws;   // 65536 bf16 = 128 KiB scratch
  prep_weights<<<256, 256, 0, stream>>>(wqkv, wproj, wbf);
  winattn_main<<<8192, 256, 0, stream>>>(x, wbf, wbf + 49152, bproj, out);
}